// Round 8
// baseline (384.810 us; speedup 1.0000x reference)
//
#include <hip/hip_runtime.h>

typedef __bf16 bf16x8 __attribute__((ext_vector_type(8)));
typedef float f32x4 __attribute__((ext_vector_type(4)));
typedef unsigned short u16;
typedef unsigned int u32;
typedef u32 u32x4 __attribute__((ext_vector_type(4)));

#define B_ 2
#define T_ 2048
#define C_ 1024
#define H_ 16
#define D_ 64
// 0.125 * log2(e): folded into Q so attn softmax runs in exp2 domain
#define QSCALE 0.18033688011112042f

__device__ __forceinline__ u16 f2bf(float f) {
    u32 u = __builtin_bit_cast(u32, f);
    u += 0x7fffu + ((u >> 16) & 1u);
    return (u16)(u >> 16);
}

__device__ __forceinline__ f32x4 mfma16(bf16x8 a, bf16x8 b, f32x4 c) {
    return __builtin_amdgcn_mfma_f32_16x16x32_bf16(a, b, c, 0, 0, 0);
}

// async global->LDS, 16B per lane; LDS dest = wave-uniform base + lane*16
__device__ __forceinline__ void gll16(const u16* g, u16* l) {
    __builtin_amdgcn_global_load_lds((const __attribute__((address_space(1))) unsigned int*)g,
                                     (__attribute__((address_space(3))) unsigned int*)l,
                                     16, 0, 0);
}

// ---------------- fused prep: cast x + transpose w_qkv + transpose w_proj ----------------
// grid 2048 x 256: blocks 0..1023 cast x (4096 elem each); 1024..1791 w_qkv
// transpose tiles (48x16); 1792..2047 w_proj transpose tiles (16x16).
__global__ __launch_bounds__(256) void prep_kernel(const float* __restrict__ x,
                                                   const float* __restrict__ w_qkv,
                                                   const float* __restrict__ w_proj,
                                                   u16* __restrict__ x_bf,
                                                   u16* __restrict__ wqkv_t,
                                                   u16* __restrict__ wproj_t) {
    __shared__ float tile[64][65];
    int bid = blockIdx.x;
    int t = threadIdx.x;
    if (bid < 1024) {
        int base = bid * 4096 + t * 4;
#pragma unroll
        for (int it = 0; it < 4; ++it) {
            int i = base + it * 1024;
            float4 v = *(const float4*)(x + i);
            x_bf[i + 0] = f2bf(v.x);
            x_bf[i + 1] = f2bf(v.y);
            x_bf[i + 2] = f2bf(v.z);
            x_bf[i + 3] = f2bf(v.w);
        }
        return;
    }
    const float* in;
    u16* out;
    int N, tidx;
    if (bid < 1792) { in = w_qkv; out = wqkv_t; N = 3 * C_; tidx = bid - 1024; }
    else            { in = w_proj; out = wproj_t; N = C_;  tidx = bid - 1792; }
    int ntiles = N / 64;
    int n0 = (tidx % ntiles) * 64, k0 = (tidx / ntiles) * 64;
    int c = t & 63, r0 = t >> 6;
    for (int i = 0; i < 16; ++i) {
        int r = r0 * 16 + i;
        tile[r][c] = in[(size_t)(k0 + r) * N + n0 + c];
    }
    __syncthreads();
    for (int i = 0; i < 16; ++i) {
        int rn = r0 * 16 + i;
        out[(size_t)(n0 + rn) * C_ + k0 + c] = f2bf(tile[c][rn]);
    }
}

// ---------------- fused QKV GEMM (gemm_bt body verbatim, verified r3/r5/r7) ----------------
// grid 768 x 256. blocks 0..511: QK gemm  C[4096,2048] = x * wqk^T -> Q,K scatter.
//                 blocks 512..767: Vt gemm C[1024,4096] = wv^T * x^T -> Vt[bh,d,t].
// Both K=1024, 128x128 tiles. 768 blocks = 3 blocks/CU co-resident.
__global__ __launch_bounds__(256) void qkv_gemm(const u16* __restrict__ x_bf,
                                                const u16* __restrict__ wqkv_t,
                                                u16* __restrict__ Qo, u16* __restrict__ Ko,
                                                u16* __restrict__ Vto) {
    __shared__ __align__(16) u16 As[128 * 32];
    __shared__ __align__(16) u16 Bs[128 * 32];
    int bid = blockIdx.x;
    const u16 *A, *Bt;
    int m0, n0;
    bool qk = (bid < 512);
    if (qk) {
        A = x_bf; Bt = wqkv_t;
        n0 = (bid & 15) * 128; m0 = (bid >> 4) * 128;
    } else {
        int vb = bid - 512;
        A = wqkv_t + 2048 * 1024; Bt = x_bf;
        n0 = (vb & 31) * 128; m0 = (vb >> 5) * 128;
    }
    const int K = 1024;
    int t = threadIdx.x;
    int wave = t >> 6, lane = t & 63, lr = lane & 15, quad = lane >> 4;
    int wm = (wave >> 1) * 64, wn = (wave & 1) * 64;

    int srow = lane >> 2;
    int sgl = (lane & 3) ^ (srow & 3);

    f32x4 acc[4][4];
    for (int i = 0; i < 4; ++i)
        for (int j = 0; j < 4; ++j) acc[i][j] = (f32x4){0.f, 0.f, 0.f, 0.f};

    int swz = (quad ^ (lr & 3)) * 8;

    for (int kb = 0; kb < K; kb += 32) {
        __syncthreads();
        for (int i = 0; i < 2; ++i) {
            int c = wave * 2 + i;
            int row = c * 16 + srow;
            gll16(&A[(size_t)(m0 + row) * K + kb + sgl * 8], &As[c * 512]);
            gll16(&Bt[(size_t)(n0 + row) * K + kb + sgl * 8], &Bs[c * 512]);
        }
        __syncthreads();
        bf16x8 af[4], bfr[4];
        for (int mt = 0; mt < 4; ++mt)
            af[mt] = *(const bf16x8*)&As[(wm + mt * 16 + lr) * 32 + swz];
        for (int nt = 0; nt < 4; ++nt)
            bfr[nt] = *(const bf16x8*)&Bs[(wn + nt * 16 + lr) * 32 + swz];
        for (int mt = 0; mt < 4; ++mt)
            for (int nt = 0; nt < 4; ++nt) acc[mt][nt] = mfma16(af[mt], bfr[nt], acc[mt][nt]);
    }

    for (int mt = 0; mt < 4; ++mt) {
        for (int nt = 0; nt < 4; ++nt) {
            for (int r = 0; r < 4; ++r) {
                int row = m0 + wm + mt * 16 + quad * 4 + r;
                int col = n0 + wn + nt * 16 + lr;
                float v = acc[mt][nt][r];
                if (qk) {
                    int part = col >> 10;  // 0:q 1:k
                    int rem = col & 1023;
                    int h = rem >> 6, d = rem & 63;
                    int b = row >> 11, tt = row & 2047;
                    int bh = b * H_ + h;
                    if (part == 0) Qo[((size_t)(bh * T_ + tt)) * D_ + d] = f2bf(v * QSCALE);
                    else           Ko[((size_t)(bh * T_ + tt)) * D_ + d] = f2bf(v);
                } else {
                    int b = col >> 11, tt = col & 2047;
                    int h = row >> 6, d = row & 63;
                    Vto[(((size_t)(b * H_ + h)) * D_ + d) * T_ + tt] = f2bf(v);
                }
            }
        }
    }
}

// ---------------- GEMM 128x64 tile (verified r7): proj epilogue ----------------
__global__ __launch_bounds__(256) void gemm64_proj(const u16* __restrict__ A,
                                                   const u16* __restrict__ Bt,
                                                   float* __restrict__ Cout,
                                                   const float* __restrict__ bias,
                                                   int M, int N, int K) {
    __shared__ __align__(16) u16 As[128 * 32];
    __shared__ __align__(16) u16 Bs[64 * 32];
    int m0 = blockIdx.y * 128, n0 = blockIdx.x * 64;
    int t = threadIdx.x;
    int wave = t >> 6, lane = t & 63, lr = lane & 15, quad = lane >> 4;
    int srow = lane >> 2;
    int sgl = (lane & 3) ^ (srow & 3);
    int swz = (quad ^ (lr & 3)) * 8;

    f32x4 acc[2][4];
#pragma unroll
    for (int i = 0; i < 2; ++i)
#pragma unroll
        for (int j = 0; j < 4; ++j) acc[i][j] = (f32x4){0.f, 0.f, 0.f, 0.f};

    for (int kb = 0; kb < K; kb += 32) {
        __syncthreads();
#pragma unroll
        for (int i = 0; i < 2; ++i) {
            int c = wave * 2 + i;
            int row = c * 16 + srow;
            gll16(&A[(size_t)(m0 + row) * K + kb + sgl * 8], &As[c * 512]);
        }
        {
            int row = wave * 16 + srow;
            gll16(&Bt[(size_t)(n0 + row) * K + kb + sgl * 8], &Bs[wave * 512]);
        }
        __syncthreads();
        bf16x8 af[2], bfr[4];
#pragma unroll
        for (int mt = 0; mt < 2; ++mt)
            af[mt] = *(const bf16x8*)&As[(wave * 32 + mt * 16 + lr) * 32 + swz];
#pragma unroll
        for (int nt = 0; nt < 4; ++nt)
            bfr[nt] = *(const bf16x8*)&Bs[(nt * 16 + lr) * 32 + swz];
#pragma unroll
        for (int mt = 0; mt < 2; ++mt)
#pragma unroll
            for (int nt = 0; nt < 4; ++nt) acc[mt][nt] = mfma16(af[mt], bfr[nt], acc[mt][nt]);
    }

#pragma unroll
    for (int mt = 0; mt < 2; ++mt) {
#pragma unroll
        for (int nt = 0; nt < 4; ++nt) {
#pragma unroll
            for (int r = 0; r < 4; ++r) {
                int row = m0 + wave * 32 + mt * 16 + quad * 4 + r;
                int col = n0 + nt * 16 + lr;
                Cout[(size_t)row * N + col] = acc[mt][nt][r] + bias[col];
            }
        }
    }
}

// ---------------- flash attention (verified r7, verbatim) ----------------
// grid 1024 (32 bh x 32 q-tiles of 64 rows, heavy-first); block 256 = 4 waves, wave = 16 q-rows.
// K/V 64x64 tiles double-buffered in LDS via gll16. S^T = K Q^T (per-lane softmax state).
// No-max softmax (exp2 domain, scores bounded). P round-trip per-wave u32 LDS + fences.
__global__ __launch_bounds__(256, 4) void attn_kernel(const u16* __restrict__ Q,
                                                      const u16* __restrict__ Kb,
                                                      const u16* __restrict__ Vt,
                                                      u16* __restrict__ Y) {
    __shared__ __align__(16) u16 Kls[2][64 * 64];
    __shared__ __align__(16) u16 Vls[2][64 * 64];
    __shared__ __align__(16) u32 Pls[4][512];
    int qt = 31 - (blockIdx.x >> 5);  // heavy-first
    int bh = blockIdx.x & 31;
    int t = threadIdx.x, wave = t >> 6, lane = t & 63, lr = lane & 15, quad = lane >> 4;

    const u16* kbase = Kb + (size_t)bh * (T_ * D_);
    const u16* vbase = Vt + (size_t)bh * (D_ * T_);
    const u16* Qg = Q + ((size_t)bh * T_ + qt * 64 + wave * 16 + lr) * D_;
    bf16x8 qfl = *(const bf16x8*)(Qg + quad * 8);
    bf16x8 qfh = *(const bf16x8*)(Qg + 32 + quad * 8);

    float lsum = 0.f;
    f32x4 o[4];
#pragma unroll
    for (int dt = 0; dt < 4; ++dt) o[dt] = (f32x4){0.f, 0.f, 0.f, 0.f};

    int srow = lane >> 3;
    int sgl = (lane & 7) ^ srow;
    int swz1 = (quad ^ (lr & 7)) * 8;
    int swz2 = ((quad + 4) ^ (lr & 7)) * 8;
    u32* pw = &Pls[wave][0];
    int pwbase = lr * 32 + (quad & 1) * 2;
    int rg1 = (quad ^ (lr & 7)) << 2;
    int rg2 = ((quad + 4) ^ (lr & 7)) << 2;

    for (int i = 0; i < 2; ++i) {
        int c = wave * 2 + i;
        int row = c * 8 + srow;
        gll16(kbase + (size_t)row * D_ + sgl * 8, &Kls[0][c * 512]);
        gll16(vbase + (size_t)row * T_ + sgl * 8, &Vls[0][c * 512]);
    }

    for (int kt = 0; kt <= qt; ++kt) {
        int buf = kt & 1;
        __syncthreads();
        if (kt < qt) {
            int nk = kt + 1;
            for (int i = 0; i < 2; ++i) {
                int c = wave * 2 + i;
                int row = c * 8 + srow;
                gll16(kbase + (size_t)(nk * 64 + row) * D_ + sgl * 8, &Kls[buf ^ 1][c * 512]);
                gll16(vbase + (size_t)row * T_ + nk * 64 + sgl * 8, &Vls[buf ^ 1][c * 512]);
            }
        }
        bf16x8 kf0[4], kf1[4], vf0[4], vf1[4];
#pragma unroll
        for (int st = 0; st < 4; ++st) {
            const u16* kp = &Kls[buf][(st * 16 + lr) * 64];
            kf0[st] = *(const bf16x8*)(kp + swz1);
            kf1[st] = *(const bf16x8*)(kp + swz2);
            const u16* vp = &Vls[buf][(st * 16 + lr) * 64];
            vf0[st] = *(const bf16x8*)(vp + swz1);
            vf1[st] = *(const bf16x8*)(vp + swz2);
        }
        f32x4 s[4];
#pragma unroll
        for (int st = 0; st < 4; ++st) {
            s[st] = mfma16(kf0[st], qfl, (f32x4){0.f, 0.f, 0.f, 0.f});
            s[st] = mfma16(kf1[st], qfh, s[st]);
        }
        if (kt == qt) {
            int qloc = wave * 16 + lr;
#pragma unroll
            for (int st = 0; st < 4; ++st)
#pragma unroll
                for (int r = 0; r < 4; ++r) {
                    if (st * 16 + quad * 4 + r > qloc) s[st][r] = -__builtin_inff();
                }
        }
        float sum = 0.f;
#pragma unroll
        for (int st = 0; st < 4; ++st)
#pragma unroll
            for (int r = 0; r < 4; ++r) {
                float p = __builtin_amdgcn_exp2f(s[st][r]);
                s[st][r] = p;
                sum += p;
            }
        sum += __shfl_xor(sum, 16);
        sum += __shfl_xor(sum, 32);
        lsum += sum;
        asm volatile("" ::: "memory");
#pragma unroll
        for (int st = 0; st < 4; ++st)
#pragma unroll
            for (int rp = 0; rp < 2; ++rp) {
                u32 lo = f2bf(s[st][2 * rp]);
                u32 hi = f2bf(s[st][2 * rp + 1]);
                pw[pwbase + (((st * 2 + (quad >> 1)) ^ (lr & 7)) << 2) + rp] = lo | (hi << 16);
            }
        asm volatile("" ::: "memory");
        const u32* prow = &pw[lr * 32];
        u32x4 plo = *(const u32x4*)(prow + rg1);
        u32x4 phi = *(const u32x4*)(prow + rg2);
        asm volatile("" ::: "memory");
        bf16x8 pfl = __builtin_bit_cast(bf16x8, plo);
        bf16x8 pfh = __builtin_bit_cast(bf16x8, phi);
#pragma unroll
        for (int dt = 0; dt < 4; ++dt) {
            o[dt] = mfma16(vf0[dt], pfl, o[dt]);
            o[dt] = mfma16(vf1[dt], pfh, o[dt]);
        }
    }

    int b = bh >> 4, h = bh & 15;
    float inv = 1.0f / lsum;
    asm volatile("" ::: "memory");
#pragma unroll
    for (int dt = 0; dt < 4; ++dt)
#pragma unroll
        for (int rp = 0; rp < 2; ++rp) {
            u32 lo = f2bf(o[dt][2 * rp] * inv);
            u32 hi = f2bf(o[dt][2 * rp + 1] * inv);
            pw[pwbase + (((dt * 2 + (quad >> 1)) ^ (lr & 7)) << 2) + rp] = lo | (hi << 16);
        }
    asm volatile("" ::: "memory");
    {
        int query = lane >> 2, wsel = lane & 3;
        const u32* prow = &pw[query * 32];
        u32x4 w0 = *(const u32x4*)(prow + (((wsel * 2) ^ (query & 7)) << 2));
        u32x4 w1 = *(const u32x4*)(prow + (((wsel * 2 + 1) ^ (query & 7)) << 2));
        u32* dst = (u32*)(Y + ((size_t)(b * T_ + qt * 64 + wave * 16 + query)) * C_ + h * 64 + wsel * 16);
        *(u32x4*)dst = w0;
        *(u32x4*)(dst + 4) = w1;
    }
}

extern "C" void kernel_launch(void* const* d_in, const int* in_sizes, int n_in,
                              void* d_out, int out_size, void* d_ws, size_t ws_size,
                              hipStream_t stream) {
    const float* x      = (const float*)d_in[0];
    const float* w_qkv  = (const float*)d_in[1];
    const float* w_proj = (const float*)d_in[2];
    const float* b_proj = (const float*)d_in[3];
    float* out = (float*)d_out;

    char* ws = (char*)d_ws;
    u16* x_bf    = (u16*)(ws + 0);          // 8 MB
    u16* wqkv_t  = (u16*)(ws + 8388608);    // 6 MB [n=3072][k=1024]
    u16* wproj_t = (u16*)(ws + 14680064);   // 2 MB
    u16* q_bf    = (u16*)(ws + 16777216);   // 8 MB  [bh][t][d] (pre-scaled)
    u16* k_bf    = (u16*)(ws + 25165824);   // 8 MB  [bh][t][d]
    u16* vt_bf   = (u16*)(ws + 33554432);   // 8 MB  [bh][d][t]
    u16* y_bf    = (u16*)(ws + 41943040);   // 8 MB  [b*t][c]

    const int M = B_ * T_;  // 4096

    // fused prep: cast + both weight transposes (2048 blocks)
    prep_kernel<<<2048, 256, 0, stream>>>(x, w_qkv, w_proj, x_bf, wqkv_t, wproj_t);

    // fused QKV: QK gemm (512 blocks) + Vt gemm (256 blocks) co-resident
    qkv_gemm<<<768, 256, 0, stream>>>(x_bf, wqkv_t, q_bf, k_bf, vt_bf);

    // flash attention: 1024 4-wave blocks
    attn_kernel<<<32 * (T_ / 64), 256, 0, stream>>>(q_bf, k_bf, vt_bf, y_bf);

    // proj gemm: [4096,1024] x [1024,1024]^T + bias (512 blocks)
    gemm64_proj<<<dim3(C_ / 64, M / 128), 256, 0, stream>>>(
        y_bf, wproj_t, out, b_proj, M, C_, C_);
}

// Round 9
// 184.984 us; speedup vs baseline: 2.0802x; 2.0802x over previous
//
#include <hip/hip_runtime.h>

typedef __bf16 bf16x8 __attribute__((ext_vector_type(8)));
typedef float f32x4 __attribute__((ext_vector_type(4)));
typedef unsigned short u16;
typedef unsigned int u32;
typedef u32 u32x4 __attribute__((ext_vector_type(4)));
typedef u16 u16x8 __attribute__((ext_vector_type(8)));

#define B_ 2
#define T_ 2048
#define C_ 1024
#define H_ 16
#define D_ 64
// 0.125 * log2(e): folded into Q so attn softmax runs in exp2 domain
#define QSCALE 0.18033688011112042f

__device__ __forceinline__ u16 f2bf(float f) {
    u32 u = __builtin_bit_cast(u32, f);
    u += 0x7fffu + ((u >> 16) & 1u);
    return (u16)(u >> 16);
}

__device__ __forceinline__ f32x4 mfma16(bf16x8 a, bf16x8 b, f32x4 c) {
    return __builtin_amdgcn_mfma_f32_16x16x32_bf16(a, b, c, 0, 0, 0);
}

// async global->LDS, 16B per lane; LDS dest = wave-uniform base + lane*16
__device__ __forceinline__ void gll16(const u16* g, u16* l) {
    __builtin_amdgcn_global_load_lds((const __attribute__((address_space(1))) unsigned int*)g,
                                     (__attribute__((address_space(3))) unsigned int*)l,
                                     16, 0, 0);
}

// ---------------- fused prep (verified r8): cast x + transpose w_qkv + w_proj ----------------
__global__ __launch_bounds__(256) void prep_kernel(const float* __restrict__ x,
                                                   const float* __restrict__ w_qkv,
                                                   const float* __restrict__ w_proj,
                                                   u16* __restrict__ x_bf,
                                                   u16* __restrict__ wqkv_t,
                                                   u16* __restrict__ wproj_t) {
    __shared__ float tile[64][65];
    int bid = blockIdx.x;
    int t = threadIdx.x;
    if (bid < 1024) {
        int base = bid * 4096 + t * 4;
#pragma unroll
        for (int it = 0; it < 4; ++it) {
            int i = base + it * 1024;
            float4 v = *(const float4*)(x + i);
            x_bf[i + 0] = f2bf(v.x);
            x_bf[i + 1] = f2bf(v.y);
            x_bf[i + 2] = f2bf(v.z);
            x_bf[i + 3] = f2bf(v.w);
        }
        return;
    }
    const float* in;
    u16* out;
    int N, tidx;
    if (bid < 1792) { in = w_qkv; out = wqkv_t; N = 3 * C_; tidx = bid - 1024; }
    else            { in = w_proj; out = wproj_t; N = C_;  tidx = bid - 1792; }
    int ntiles = N / 64;
    int n0 = (tidx % ntiles) * 64, k0 = (tidx / ntiles) * 64;
    int c = t & 63, r0 = t >> 6;
    for (int i = 0; i < 16; ++i) {
        int r = r0 * 16 + i;
        tile[r][c] = in[(size_t)(k0 + r) * N + n0 + c];
    }
    __syncthreads();
    for (int i = 0; i < 16; ++i) {
        int rn = r0 * 16 + i;
        out[(size_t)(n0 + rn) * C_ + k0 + c] = f2bf(tile[c][rn]);
    }
}

// ---------------- QK GEMM 128x128 (main loop verified r3/r5/r7) ----------------
// NEW epilogue: acc -> per-wave LDS (u16, reuse staging smem) -> u16x8 reads ->
// 32B/lane contiguous global stores (full 128B lines per 4 lanes). No u16 scatter.
__global__ __launch_bounds__(256) void gemm_qk(const u16* __restrict__ A,
                                               const u16* __restrict__ Bt,
                                               u16* __restrict__ Qo, u16* __restrict__ Ko) {
    __shared__ __align__(16) u16 smem[8192];   // As = smem[0:4096], Bs = smem[4096:8192]
    u16* As = smem;
    u16* Bs = smem + 4096;
    const int K = 1024;
    int m0 = blockIdx.y * 128, n0 = blockIdx.x * 128;
    int t = threadIdx.x;
    int wave = t >> 6, lane = t & 63, lr = lane & 15, quad = lane >> 4;
    int wm = (wave >> 1) * 64, wn = (wave & 1) * 64;

    int srow = lane >> 2;
    int sgl = (lane & 3) ^ (srow & 3);

    f32x4 acc[4][4];
    for (int i = 0; i < 4; ++i)
        for (int j = 0; j < 4; ++j) acc[i][j] = (f32x4){0.f, 0.f, 0.f, 0.f};

    int swz = (quad ^ (lr & 3)) * 8;

    for (int kb = 0; kb < K; kb += 32) {
        __syncthreads();
        for (int i = 0; i < 2; ++i) {
            int c = wave * 2 + i;
            int row = c * 16 + srow;
            gll16(&A[(size_t)(m0 + row) * K + kb + sgl * 8], &As[c * 512]);
            gll16(&Bt[(size_t)(n0 + row) * K + kb + sgl * 8], &Bs[c * 512]);
        }
        __syncthreads();
        bf16x8 af[4], bfr[4];
        for (int mt = 0; mt < 4; ++mt)
            af[mt] = *(const bf16x8*)&As[(wm + mt * 16 + lr) * 32 + swz];
        for (int nt = 0; nt < 4; ++nt)
            bfr[nt] = *(const bf16x8*)&Bs[(wn + nt * 16 + lr) * 32 + swz];
        for (int mt = 0; mt < 4; ++mt)
            for (int nt = 0; nt < 4; ++nt) acc[mt][nt] = mfma16(af[mt], bfr[nt], acc[mt][nt]);
    }

    // transposed epilogue: 4 passes of 16 rows; per-wave 1152-u16 buffer in smem
    __syncthreads();  // all waves done reading As/Bs
    u16* eb = smem + wave * 1152;          // 2304B per wave, 9216B total <= 16KB
    int row = lane >> 2;                   // 0..15
    int cb = (lane & 3) * 16;              // col base within wave's 64-col span
    int colg = n0 + wn;                    // wave-uniform 64-aligned
    int part = colg >> 10;                 // 0:q 1:k
    int h = (colg & 1023) >> 6;
    float sc = (part == 0) ? QSCALE : 1.0f;
    u16* outb = (part == 0) ? Qo : Ko;
#pragma unroll
    for (int p = 0; p < 4; ++p) {
        asm volatile("" ::: "memory");
#pragma unroll
        for (int nt = 0; nt < 4; ++nt)
#pragma unroll
            for (int r = 0; r < 4; ++r)
                eb[(quad * 4 + r) * 72 + nt * 16 + lr] = f2bf(acc[p][nt][r] * sc);
        asm volatile("" ::: "memory");
        u16x8 va = *(const u16x8*)(eb + row * 72 + cb);
        u16x8 vb = *(const u16x8*)(eb + row * 72 + cb + 8);
        asm volatile("" ::: "memory");
        int rowg = m0 + wm + p * 16 + row;
        int bb = rowg >> 11, tt = rowg & 2047;
        int bh = bb * H_ + h;
        u32* dst = (u32*)(outb + ((size_t)(bh * T_ + tt)) * D_ + cb);
        *(u32x4*)dst = __builtin_bit_cast(u32x4, va);
        *(u32x4*)(dst + 4) = __builtin_bit_cast(u32x4, vb);
    }
}

// ---------------- GEMM 128x64 tile (main loop verified r7) ----------------
// MODE 2: proj epilogue (f32 + bias, unchanged). MODE 3: Vt epilogue via LDS transpose.
template <int MODE>
__global__ __launch_bounds__(256) void gemm64(const u16* __restrict__ A,
                                              const u16* __restrict__ Bt,
                                              float* __restrict__ Cout,
                                              u16* __restrict__ Vto,
                                              const float* __restrict__ bias,
                                              int M, int N, int K) {
    __shared__ __align__(16) u16 smem[6144];   // As = [0:4096], Bs = [4096:6144]
    u16* As = smem;
    u16* Bs = smem + 4096;
    int m0 = blockIdx.y * 128, n0 = blockIdx.x * 64;
    int t = threadIdx.x;
    int wave = t >> 6, lane = t & 63, lr = lane & 15, quad = lane >> 4;
    int srow = lane >> 2;
    int sgl = (lane & 3) ^ (srow & 3);
    int swz = (quad ^ (lr & 3)) * 8;

    f32x4 acc[2][4];
#pragma unroll
    for (int i = 0; i < 2; ++i)
#pragma unroll
        for (int j = 0; j < 4; ++j) acc[i][j] = (f32x4){0.f, 0.f, 0.f, 0.f};

    for (int kb = 0; kb < K; kb += 32) {
        __syncthreads();
#pragma unroll
        for (int i = 0; i < 2; ++i) {
            int c = wave * 2 + i;
            int row = c * 16 + srow;
            gll16(&A[(size_t)(m0 + row) * K + kb + sgl * 8], &As[c * 512]);
        }
        {
            int row = wave * 16 + srow;
            gll16(&Bt[(size_t)(n0 + row) * K + kb + sgl * 8], &Bs[wave * 512]);
        }
        __syncthreads();
        bf16x8 af[2], bfr[4];
#pragma unroll
        for (int mt = 0; mt < 2; ++mt)
            af[mt] = *(const bf16x8*)&As[(wave * 32 + mt * 16 + lr) * 32 + swz];
#pragma unroll
        for (int nt = 0; nt < 4; ++nt)
            bfr[nt] = *(const bf16x8*)&Bs[(nt * 16 + lr) * 32 + swz];
#pragma unroll
        for (int mt = 0; mt < 2; ++mt)
#pragma unroll
            for (int nt = 0; nt < 4; ++nt) acc[mt][nt] = mfma16(af[mt], bfr[nt], acc[mt][nt]);
    }

    if (MODE == 2) {
#pragma unroll
        for (int mt = 0; mt < 2; ++mt)
#pragma unroll
            for (int nt = 0; nt < 4; ++nt)
#pragma unroll
                for (int r = 0; r < 4; ++r) {
                    int rowg = m0 + wave * 32 + mt * 16 + quad * 4 + r;
                    int col = n0 + nt * 16 + lr;
                    Cout[(size_t)rowg * N + col] = acc[mt][nt][r] + bias[col];
                }
    } else {
        // Vt transposed epilogue: 2 passes of 16 rows(d); lanes store 16 consecutive tokens
        __syncthreads();
        u16* eb = smem + wave * 1152;      // 4*1152 = 4608 u16 <= 6144
        int row = lane >> 2;
        int cb = (lane & 3) * 16;
#pragma unroll
        for (int p = 0; p < 2; ++p) {
            asm volatile("" ::: "memory");
#pragma unroll
            for (int nt = 0; nt < 4; ++nt)
#pragma unroll
                for (int r = 0; r < 4; ++r)
                    eb[(quad * 4 + r) * 72 + nt * 16 + lr] = f2bf(acc[p][nt][r]);
            asm volatile("" ::: "memory");
            u16x8 va = *(const u16x8*)(eb + row * 72 + cb);
            u16x8 vb = *(const u16x8*)(eb + row * 72 + cb + 8);
            asm volatile("" ::: "memory");
            int rowg = m0 + wave * 32 + p * 16 + row;   // d_global
            int h = rowg >> 6, d = rowg & 63;
            int tg = n0 + cb;                            // token base (16-aligned)
            int bb = tg >> 11, tt = tg & 2047;
            u32* dst = (u32*)(Vto + (((size_t)(bb * H_ + h)) * D_ + d) * T_ + tt);
            *(u32x4*)dst = __builtin_bit_cast(u32x4, va);
            *(u32x4*)(dst + 4) = __builtin_bit_cast(u32x4, vb);
        }
    }
}

// ---------------- flash attention (verified r7, verbatim) ----------------
__global__ __launch_bounds__(256, 4) void attn_kernel(const u16* __restrict__ Q,
                                                      const u16* __restrict__ Kb,
                                                      const u16* __restrict__ Vt,
                                                      u16* __restrict__ Y) {
    __shared__ __align__(16) u16 Kls[2][64 * 64];
    __shared__ __align__(16) u16 Vls[2][64 * 64];
    __shared__ __align__(16) u32 Pls[4][512];
    int qt = 31 - (blockIdx.x >> 5);  // heavy-first
    int bh = blockIdx.x & 31;
    int t = threadIdx.x, wave = t >> 6, lane = t & 63, lr = lane & 15, quad = lane >> 4;

    const u16* kbase = Kb + (size_t)bh * (T_ * D_);
    const u16* vbase = Vt + (size_t)bh * (D_ * T_);
    const u16* Qg = Q + ((size_t)bh * T_ + qt * 64 + wave * 16 + lr) * D_;
    bf16x8 qfl = *(const bf16x8*)(Qg + quad * 8);
    bf16x8 qfh = *(const bf16x8*)(Qg + 32 + quad * 8);

    float lsum = 0.f;
    f32x4 o[4];
#pragma unroll
    for (int dt = 0; dt < 4; ++dt) o[dt] = (f32x4){0.f, 0.f, 0.f, 0.f};

    int srow = lane >> 3;
    int sgl = (lane & 7) ^ srow;
    int swz1 = (quad ^ (lr & 7)) * 8;
    int swz2 = ((quad + 4) ^ (lr & 7)) * 8;
    u32* pw = &Pls[wave][0];
    int pwbase = lr * 32 + (quad & 1) * 2;
    int rg1 = (quad ^ (lr & 7)) << 2;
    int rg2 = ((quad + 4) ^ (lr & 7)) << 2;

    for (int i = 0; i < 2; ++i) {
        int c = wave * 2 + i;
        int row = c * 8 + srow;
        gll16(kbase + (size_t)row * D_ + sgl * 8, &Kls[0][c * 512]);
        gll16(vbase + (size_t)row * T_ + sgl * 8, &Vls[0][c * 512]);
    }

    for (int kt = 0; kt <= qt; ++kt) {
        int buf = kt & 1;
        __syncthreads();
        if (kt < qt) {
            int nk = kt + 1;
            for (int i = 0; i < 2; ++i) {
                int c = wave * 2 + i;
                int row = c * 8 + srow;
                gll16(kbase + (size_t)(nk * 64 + row) * D_ + sgl * 8, &Kls[buf ^ 1][c * 512]);
                gll16(vbase + (size_t)row * T_ + nk * 64 + sgl * 8, &Vls[buf ^ 1][c * 512]);
            }
        }
        bf16x8 kf0[4], kf1[4], vf0[4], vf1[4];
#pragma unroll
        for (int st = 0; st < 4; ++st) {
            const u16* kp = &Kls[buf][(st * 16 + lr) * 64];
            kf0[st] = *(const bf16x8*)(kp + swz1);
            kf1[st] = *(const bf16x8*)(kp + swz2);
            const u16* vp = &Vls[buf][(st * 16 + lr) * 64];
            vf0[st] = *(const bf16x8*)(vp + swz1);
            vf1[st] = *(const bf16x8*)(vp + swz2);
        }
        f32x4 s[4];
#pragma unroll
        for (int st = 0; st < 4; ++st) {
            s[st] = mfma16(kf0[st], qfl, (f32x4){0.f, 0.f, 0.f, 0.f});
            s[st] = mfma16(kf1[st], qfh, s[st]);
        }
        if (kt == qt) {
            int qloc = wave * 16 + lr;
#pragma unroll
            for (int st = 0; st < 4; ++st)
#pragma unroll
                for (int r = 0; r < 4; ++r) {
                    if (st * 16 + quad * 4 + r > qloc) s[st][r] = -__builtin_inff();
                }
        }
        float sum = 0.f;
#pragma unroll
        for (int st = 0; st < 4; ++st)
#pragma unroll
            for (int r = 0; r < 4; ++r) {
                float p = __builtin_amdgcn_exp2f(s[st][r]);
                s[st][r] = p;
                sum += p;
            }
        sum += __shfl_xor(sum, 16);
        sum += __shfl_xor(sum, 32);
        lsum += sum;
        asm volatile("" ::: "memory");
#pragma unroll
        for (int st = 0; st < 4; ++st)
#pragma unroll
            for (int rp = 0; rp < 2; ++rp) {
                u32 lo = f2bf(s[st][2 * rp]);
                u32 hi = f2bf(s[st][2 * rp + 1]);
                pw[pwbase + (((st * 2 + (quad >> 1)) ^ (lr & 7)) << 2) + rp] = lo | (hi << 16);
            }
        asm volatile("" ::: "memory");
        const u32* prow = &pw[lr * 32];
        u32x4 plo = *(const u32x4*)(prow + rg1);
        u32x4 phi = *(const u32x4*)(prow + rg2);
        asm volatile("" ::: "memory");
        bf16x8 pfl = __builtin_bit_cast(bf16x8, plo);
        bf16x8 pfh = __builtin_bit_cast(bf16x8, phi);
#pragma unroll
        for (int dt = 0; dt < 4; ++dt) {
            o[dt] = mfma16(vf0[dt], pfl, o[dt]);
            o[dt] = mfma16(vf1[dt], pfh, o[dt]);
        }
    }

    int b = bh >> 4, h = bh & 15;
    float inv = 1.0f / lsum;
    asm volatile("" ::: "memory");
#pragma unroll
    for (int dt = 0; dt < 4; ++dt)
#pragma unroll
        for (int rp = 0; rp < 2; ++rp) {
            u32 lo = f2bf(o[dt][2 * rp] * inv);
            u32 hi = f2bf(o[dt][2 * rp + 1] * inv);
            pw[pwbase + (((dt * 2 + (quad >> 1)) ^ (lr & 7)) << 2) + rp] = lo | (hi << 16);
        }
    asm volatile("" ::: "memory");
    {
        int query = lane >> 2, wsel = lane & 3;
        const u32* prow = &pw[query * 32];
        u32x4 w0 = *(const u32x4*)(prow + (((wsel * 2) ^ (query & 7)) << 2));
        u32x4 w1 = *(const u32x4*)(prow + (((wsel * 2 + 1) ^ (query & 7)) << 2));
        u32* dst = (u32*)(Y + ((size_t)(b * T_ + qt * 64 + wave * 16 + query)) * C_ + h * 64 + wsel * 16);
        *(u32x4*)dst = w0;
        *(u32x4*)(dst + 4) = w1;
    }
}

extern "C" void kernel_launch(void* const* d_in, const int* in_sizes, int n_in,
                              void* d_out, int out_size, void* d_ws, size_t ws_size,
                              hipStream_t stream) {
    const float* x      = (const float*)d_in[0];
    const float* w_qkv  = (const float*)d_in[1];
    const float* w_proj = (const float*)d_in[2];
    const float* b_proj = (const float*)d_in[3];
    float* out = (float*)d_out;

    char* ws = (char*)d_ws;
    u16* x_bf    = (u16*)(ws + 0);          // 8 MB
    u16* wqkv_t  = (u16*)(ws + 8388608);    // 6 MB [n=3072][k=1024]
    u16* wproj_t = (u16*)(ws + 14680064);   // 2 MB
    u16* q_bf    = (u16*)(ws + 16777216);   // 8 MB  [bh][t][d] (pre-scaled)
    u16* k_bf    = (u16*)(ws + 25165824);   // 8 MB  [bh][t][d]
    u16* vt_bf   = (u16*)(ws + 33554432);   // 8 MB  [bh][d][t]
    u16* y_bf    = (u16*)(ws + 41943040);   // 8 MB  [b*t][c]

    const int M = B_ * T_;  // 4096

    // fused prep: cast + both weight transposes (2048 blocks)
    prep_kernel<<<2048, 256, 0, stream>>>(x, w_qkv, w_proj, x_bf, wqkv_t, wproj_t);

    // QK gemm: [4096,1024] x [2048,1024]^T -> Q,K (coalesced epilogue, 512 blocks)
    gemm_qk<<<dim3(2 * C_ / 128, M / 128), 256, 0, stream>>>(x_bf, wqkv_t, q_bf, k_bf);

    // V^T gemm: A = Wv^T [1024,1024], Bt = x [4096,1024] -> Vt[bh,d,t] (512 blocks)
    gemm64<3><<<dim3(M / 64, C_ / 128), 256, 0, stream>>>(
        wqkv_t + 2048 * 1024, x_bf, nullptr, vt_bf, nullptr, C_, M, C_);

    // flash attention: 1024 4-wave blocks
    attn_kernel<<<32 * (T_ / 64), 256, 0, stream>>>(q_bf, k_bf, vt_bf, y_bf);

    // proj gemm: [4096,1024] x [1024,1024]^T + bias (512 blocks)
    gemm64<2><<<dim3(C_ / 64, M / 128), 256, 0, stream>>>(
        y_bf, wproj_t, out, nullptr, b_proj, M, C_, C_);
}

// Round 10
// 184.116 us; speedup vs baseline: 2.0900x; 1.0047x over previous
//
#include <hip/hip_runtime.h>

typedef __bf16 bf16x8 __attribute__((ext_vector_type(8)));
typedef float f32x4 __attribute__((ext_vector_type(4)));
typedef unsigned short u16;
typedef unsigned int u32;
typedef u32 u32x4 __attribute__((ext_vector_type(4)));
typedef u16 u16x8 __attribute__((ext_vector_type(8)));

#define B_ 2
#define T_ 2048
#define C_ 1024
#define H_ 16
#define D_ 64
// 0.125 * log2(e): folded into Q so attn softmax runs in exp2 domain
#define QSCALE 0.18033688011112042f

__device__ __forceinline__ u16 f2bf(float f) {
    u32 u = __builtin_bit_cast(u32, f);
    u += 0x7fffu + ((u >> 16) & 1u);
    return (u16)(u >> 16);
}

__device__ __forceinline__ f32x4 mfma16(bf16x8 a, bf16x8 b, f32x4 c) {
    return __builtin_amdgcn_mfma_f32_16x16x32_bf16(a, b, c, 0, 0, 0);
}

// async global->LDS, 16B per lane; LDS dest = wave-uniform base + lane*16
__device__ __forceinline__ void gll16(const u16* g, u16* l) {
    __builtin_amdgcn_global_load_lds((const __attribute__((address_space(1))) unsigned int*)g,
                                     (__attribute__((address_space(3))) unsigned int*)l,
                                     16, 0, 0);
}

// ---------------- fused prep (verified r8/r9): cast x + transpose w_qkv + w_proj ----------------
__global__ __launch_bounds__(256) void prep_kernel(const float* __restrict__ x,
                                                   const float* __restrict__ w_qkv,
                                                   const float* __restrict__ w_proj,
                                                   u16* __restrict__ x_bf,
                                                   u16* __restrict__ wqkv_t,
                                                   u16* __restrict__ wproj_t) {
    __shared__ float tile[64][65];
    int bid = blockIdx.x;
    int t = threadIdx.x;
    if (bid < 1024) {
        int base = bid * 4096 + t * 4;
#pragma unroll
        for (int it = 0; it < 4; ++it) {
            int i = base + it * 1024;
            float4 v = *(const float4*)(x + i);
            x_bf[i + 0] = f2bf(v.x);
            x_bf[i + 1] = f2bf(v.y);
            x_bf[i + 2] = f2bf(v.z);
            x_bf[i + 3] = f2bf(v.w);
        }
        return;
    }
    const float* in;
    u16* out;
    int N, tidx;
    if (bid < 1792) { in = w_qkv; out = wqkv_t; N = 3 * C_; tidx = bid - 1024; }
    else            { in = w_proj; out = wproj_t; N = C_;  tidx = bid - 1792; }
    int ntiles = N / 64;
    int n0 = (tidx % ntiles) * 64, k0 = (tidx / ntiles) * 64;
    int c = t & 63, r0 = t >> 6;
    for (int i = 0; i < 16; ++i) {
        int r = r0 * 16 + i;
        tile[r][c] = in[(size_t)(k0 + r) * N + n0 + c];
    }
    __syncthreads();
    for (int i = 0; i < 16; ++i) {
        int rn = r0 * 16 + i;
        out[(size_t)(n0 + rn) * C_ + k0 + c] = f2bf(tile[c][rn]);
    }
}

// ---------------- fused QKV GEMM: QK (blocks 0..511) + Vt (blocks 512..767) ----------------
// Main loop = r3/r5/r7-verified gemm_bt 128x128 body verbatim; coalesced LDS-transpose
// epilogues (QK verbatim from r9; Vt = r9's gemm64-Vt epilogue extended to 4 passes).
// 768 blocks = 3 blocks/CU; independent halves co-resident.
__global__ __launch_bounds__(256) void qkv_gemm(const u16* __restrict__ x_bf,
                                                const u16* __restrict__ wqkv_t,
                                                u16* __restrict__ Qo, u16* __restrict__ Ko,
                                                u16* __restrict__ Vto) {
    __shared__ __align__(16) u16 smem[8192];   // As=[0:4096], Bs=[4096:8192]; epilogue reuses
    u16* As = smem;
    u16* Bs = smem + 4096;
    const int K = 1024;
    int bid = blockIdx.x;
    bool qk = (bid < 512);
    const u16 *A, *Bt;
    int m0, n0;
    if (qk) {
        A = x_bf; Bt = wqkv_t;
        n0 = (bid & 15) * 128; m0 = (bid >> 4) * 128;
    } else {
        int vb = bid - 512;
        A = wqkv_t + 2048 * 1024; Bt = x_bf;
        n0 = (vb & 31) * 128; m0 = (vb >> 5) * 128;
    }
    int t = threadIdx.x;
    int wave = t >> 6, lane = t & 63, lr = lane & 15, quad = lane >> 4;
    int wm = (wave >> 1) * 64, wn = (wave & 1) * 64;

    int srow = lane >> 2;
    int sgl = (lane & 3) ^ (srow & 3);

    f32x4 acc[4][4];
    for (int i = 0; i < 4; ++i)
        for (int j = 0; j < 4; ++j) acc[i][j] = (f32x4){0.f, 0.f, 0.f, 0.f};

    int swz = (quad ^ (lr & 3)) * 8;

    for (int kb = 0; kb < K; kb += 32) {
        __syncthreads();
        for (int i = 0; i < 2; ++i) {
            int c = wave * 2 + i;
            int row = c * 16 + srow;
            gll16(&A[(size_t)(m0 + row) * K + kb + sgl * 8], &As[c * 512]);
            gll16(&Bt[(size_t)(n0 + row) * K + kb + sgl * 8], &Bs[c * 512]);
        }
        __syncthreads();
        bf16x8 af[4], bfr[4];
        for (int mt = 0; mt < 4; ++mt)
            af[mt] = *(const bf16x8*)&As[(wm + mt * 16 + lr) * 32 + swz];
        for (int nt = 0; nt < 4; ++nt)
            bfr[nt] = *(const bf16x8*)&Bs[(wn + nt * 16 + lr) * 32 + swz];
        for (int mt = 0; mt < 4; ++mt)
            for (int nt = 0; nt < 4; ++nt) acc[mt][nt] = mfma16(af[mt], bfr[nt], acc[mt][nt]);
    }

    // coalesced transposed epilogue: 4 passes of 16 rows via per-wave LDS buffer
    __syncthreads();  // all waves done reading As/Bs
    u16* eb = smem + wave * 1152;          // 9216 u16 total <= 8192? no: 4*1152=4608 <= 8192 ok
    int row = lane >> 2;                   // 0..15
    int cb = (lane & 3) * 16;              // col offset within wave's 64-col span
    if (qk) {
        int colg = n0 + wn;                // 64-aligned
        int part = colg >> 10;             // 0:q 1:k
        int h = (colg & 1023) >> 6;
        float sc = (part == 0) ? QSCALE : 1.0f;
        u16* outb = (part == 0) ? Qo : Ko;
#pragma unroll
        for (int p = 0; p < 4; ++p) {
            asm volatile("" ::: "memory");
#pragma unroll
            for (int nt = 0; nt < 4; ++nt)
#pragma unroll
                for (int r = 0; r < 4; ++r)
                    eb[(quad * 4 + r) * 72 + nt * 16 + lr] = f2bf(acc[p][nt][r] * sc);
            asm volatile("" ::: "memory");
            u16x8 va = *(const u16x8*)(eb + row * 72 + cb);
            u16x8 vb = *(const u16x8*)(eb + row * 72 + cb + 8);
            asm volatile("" ::: "memory");
            int rowg = m0 + wm + p * 16 + row;
            int bb = rowg >> 11, tt = rowg & 2047;
            int bh = bb * H_ + h;
            u32* dst = (u32*)(outb + ((size_t)(bh * T_ + tt)) * D_ + cb);
            *(u32x4*)dst = __builtin_bit_cast(u32x4, va);
            *(u32x4*)(dst + 4) = __builtin_bit_cast(u32x4, vb);
        }
    } else {
#pragma unroll
        for (int p = 0; p < 4; ++p) {
            asm volatile("" ::: "memory");
#pragma unroll
            for (int nt = 0; nt < 4; ++nt)
#pragma unroll
                for (int r = 0; r < 4; ++r)
                    eb[(quad * 4 + r) * 72 + nt * 16 + lr] = f2bf(acc[p][nt][r]);
            asm volatile("" ::: "memory");
            u16x8 va = *(const u16x8*)(eb + row * 72 + cb);
            u16x8 vb = *(const u16x8*)(eb + row * 72 + cb + 8);
            asm volatile("" ::: "memory");
            int rowg = m0 + wm + p * 16 + row;    // d_global 0..1023
            int h = rowg >> 6, d = rowg & 63;
            int tg = n0 + wn + cb;                // token base (16-aligned, 64-span)
            int bb = tg >> 11, tt = tg & 2047;
            u32* dst = (u32*)(Vto + (((size_t)(bb * H_ + h)) * D_ + d) * T_ + tt);
            *(u32x4*)dst = __builtin_bit_cast(u32x4, va);
            *(u32x4*)(dst + 4) = __builtin_bit_cast(u32x4, vb);
        }
    }
}

// ---------------- proj GEMM 128x64 (verified r7/r9, verbatim MODE-2 path) ----------------
__global__ __launch_bounds__(256) void gemm64_proj(const u16* __restrict__ A,
                                                   const u16* __restrict__ Bt,
                                                   float* __restrict__ Cout,
                                                   const float* __restrict__ bias,
                                                   int M, int N, int K) {
    __shared__ __align__(16) u16 smem[6144];
    u16* As = smem;
    u16* Bs = smem + 4096;
    int m0 = blockIdx.y * 128, n0 = blockIdx.x * 64;
    int t = threadIdx.x;
    int wave = t >> 6, lane = t & 63, lr = lane & 15, quad = lane >> 4;
    int srow = lane >> 2;
    int sgl = (lane & 3) ^ (srow & 3);
    int swz = (quad ^ (lr & 3)) * 8;

    f32x4 acc[2][4];
#pragma unroll
    for (int i = 0; i < 2; ++i)
#pragma unroll
        for (int j = 0; j < 4; ++j) acc[i][j] = (f32x4){0.f, 0.f, 0.f, 0.f};

    for (int kb = 0; kb < K; kb += 32) {
        __syncthreads();
#pragma unroll
        for (int i = 0; i < 2; ++i) {
            int c = wave * 2 + i;
            int row = c * 16 + srow;
            gll16(&A[(size_t)(m0 + row) * K + kb + sgl * 8], &As[c * 512]);
        }
        {
            int row = wave * 16 + srow;
            gll16(&Bt[(size_t)(n0 + row) * K + kb + sgl * 8], &Bs[wave * 512]);
        }
        __syncthreads();
        bf16x8 af[2], bfr[4];
#pragma unroll
        for (int mt = 0; mt < 2; ++mt)
            af[mt] = *(const bf16x8*)&As[(wave * 32 + mt * 16 + lr) * 32 + swz];
#pragma unroll
        for (int nt = 0; nt < 4; ++nt)
            bfr[nt] = *(const bf16x8*)&Bs[(nt * 16 + lr) * 32 + swz];
#pragma unroll
        for (int mt = 0; mt < 2; ++mt)
#pragma unroll
            for (int nt = 0; nt < 4; ++nt) acc[mt][nt] = mfma16(af[mt], bfr[nt], acc[mt][nt]);
    }

#pragma unroll
    for (int mt = 0; mt < 2; ++mt)
#pragma unroll
        for (int nt = 0; nt < 4; ++nt)
#pragma unroll
            for (int r = 0; r < 4; ++r) {
                int rowg = m0 + wave * 32 + mt * 16 + quad * 4 + r;
                int col = n0 + nt * 16 + lr;
                Cout[(size_t)rowg * N + col] = acc[mt][nt][r] + bias[col];
            }
}

// ---------------- flash attention (verified r7, verbatim) ----------------
__global__ __launch_bounds__(256, 4) void attn_kernel(const u16* __restrict__ Q,
                                                      const u16* __restrict__ Kb,
                                                      const u16* __restrict__ Vt,
                                                      u16* __restrict__ Y) {
    __shared__ __align__(16) u16 Kls[2][64 * 64];
    __shared__ __align__(16) u16 Vls[2][64 * 64];
    __shared__ __align__(16) u32 Pls[4][512];
    int qt = 31 - (blockIdx.x >> 5);  // heavy-first
    int bh = blockIdx.x & 31;
    int t = threadIdx.x, wave = t >> 6, lane = t & 63, lr = lane & 15, quad = lane >> 4;

    const u16* kbase = Kb + (size_t)bh * (T_ * D_);
    const u16* vbase = Vt + (size_t)bh * (D_ * T_);
    const u16* Qg = Q + ((size_t)bh * T_ + qt * 64 + wave * 16 + lr) * D_;
    bf16x8 qfl = *(const bf16x8*)(Qg + quad * 8);
    bf16x8 qfh = *(const bf16x8*)(Qg + 32 + quad * 8);

    float lsum = 0.f;
    f32x4 o[4];
#pragma unroll
    for (int dt = 0; dt < 4; ++dt) o[dt] = (f32x4){0.f, 0.f, 0.f, 0.f};

    int srow = lane >> 3;
    int sgl = (lane & 7) ^ srow;
    int swz1 = (quad ^ (lr & 7)) * 8;
    int swz2 = ((quad + 4) ^ (lr & 7)) * 8;
    u32* pw = &Pls[wave][0];
    int pwbase = lr * 32 + (quad & 1) * 2;
    int rg1 = (quad ^ (lr & 7)) << 2;
    int rg2 = ((quad + 4) ^ (lr & 7)) << 2;

    for (int i = 0; i < 2; ++i) {
        int c = wave * 2 + i;
        int row = c * 8 + srow;
        gll16(kbase + (size_t)row * D_ + sgl * 8, &Kls[0][c * 512]);
        gll16(vbase + (size_t)row * T_ + sgl * 8, &Vls[0][c * 512]);
    }

    for (int kt = 0; kt <= qt; ++kt) {
        int buf = kt & 1;
        __syncthreads();
        if (kt < qt) {
            int nk = kt + 1;
            for (int i = 0; i < 2; ++i) {
                int c = wave * 2 + i;
                int row = c * 8 + srow;
                gll16(kbase + (size_t)(nk * 64 + row) * D_ + sgl * 8, &Kls[buf ^ 1][c * 512]);
                gll16(vbase + (size_t)row * T_ + nk * 64 + sgl * 8, &Vls[buf ^ 1][c * 512]);
            }
        }
        bf16x8 kf0[4], kf1[4], vf0[4], vf1[4];
#pragma unroll
        for (int st = 0; st < 4; ++st) {
            const u16* kp = &Kls[buf][(st * 16 + lr) * 64];
            kf0[st] = *(const bf16x8*)(kp + swz1);
            kf1[st] = *(const bf16x8*)(kp + swz2);
            const u16* vp = &Vls[buf][(st * 16 + lr) * 64];
            vf0[st] = *(const bf16x8*)(vp + swz1);
            vf1[st] = *(const bf16x8*)(vp + swz2);
        }
        f32x4 s[4];
#pragma unroll
        for (int st = 0; st < 4; ++st) {
            s[st] = mfma16(kf0[st], qfl, (f32x4){0.f, 0.f, 0.f, 0.f});
            s[st] = mfma16(kf1[st], qfh, s[st]);
        }
        if (kt == qt) {
            int qloc = wave * 16 + lr;
#pragma unroll
            for (int st = 0; st < 4; ++st)
#pragma unroll
                for (int r = 0; r < 4; ++r) {
                    if (st * 16 + quad * 4 + r > qloc) s[st][r] = -__builtin_inff();
                }
        }
        float sum = 0.f;
#pragma unroll
        for (int st = 0; st < 4; ++st)
#pragma unroll
            for (int r = 0; r < 4; ++r) {
                float p = __builtin_amdgcn_exp2f(s[st][r]);
                s[st][r] = p;
                sum += p;
            }
        sum += __shfl_xor(sum, 16);
        sum += __shfl_xor(sum, 32);
        lsum += sum;
        asm volatile("" ::: "memory");
#pragma unroll
        for (int st = 0; st < 4; ++st)
#pragma unroll
            for (int rp = 0; rp < 2; ++rp) {
                u32 lo = f2bf(s[st][2 * rp]);
                u32 hi = f2bf(s[st][2 * rp + 1]);
                pw[pwbase + (((st * 2 + (quad >> 1)) ^ (lr & 7)) << 2) + rp] = lo | (hi << 16);
            }
        asm volatile("" ::: "memory");
        const u32* prow = &pw[lr * 32];
        u32x4 plo = *(const u32x4*)(prow + rg1);
        u32x4 phi = *(const u32x4*)(prow + rg2);
        asm volatile("" ::: "memory");
        bf16x8 pfl = __builtin_bit_cast(bf16x8, plo);
        bf16x8 pfh = __builtin_bit_cast(bf16x8, phi);
#pragma unroll
        for (int dt = 0; dt < 4; ++dt) {
            o[dt] = mfma16(vf0[dt], pfl, o[dt]);
            o[dt] = mfma16(vf1[dt], pfh, o[dt]);
        }
    }

    int b = bh >> 4, h = bh & 15;
    float inv = 1.0f / lsum;
    asm volatile("" ::: "memory");
#pragma unroll
    for (int dt = 0; dt < 4; ++dt)
#pragma unroll
        for (int rp = 0; rp < 2; ++rp) {
            u32 lo = f2bf(o[dt][2 * rp] * inv);
            u32 hi = f2bf(o[dt][2 * rp + 1] * inv);
            pw[pwbase + (((dt * 2 + (quad >> 1)) ^ (lr & 7)) << 2) + rp] = lo | (hi << 16);
        }
    asm volatile("" ::: "memory");
    {
        int query = lane >> 2, wsel = lane & 3;
        const u32* prow = &pw[query * 32];
        u32x4 w0 = *(const u32x4*)(prow + (((wsel * 2) ^ (query & 7)) << 2));
        u32x4 w1 = *(const u32x4*)(prow + (((wsel * 2 + 1) ^ (query & 7)) << 2));
        u32* dst = (u32*)(Y + ((size_t)(b * T_ + qt * 64 + wave * 16 + query)) * C_ + h * 64 + wsel * 16);
        *(u32x4*)dst = w0;
        *(u32x4*)(dst + 4) = w1;
    }
}

extern "C" void kernel_launch(void* const* d_in, const int* in_sizes, int n_in,
                              void* d_out, int out_size, void* d_ws, size_t ws_size,
                              hipStream_t stream) {
    const float* x      = (const float*)d_in[0];
    const float* w_qkv  = (const float*)d_in[1];
    const float* w_proj = (const float*)d_in[2];
    const float* b_proj = (const float*)d_in[3];
    float* out = (float*)d_out;

    char* ws = (char*)d_ws;
    u16* x_bf    = (u16*)(ws + 0);          // 8 MB
    u16* wqkv_t  = (u16*)(ws + 8388608);    // 6 MB [n=3072][k=1024]
    u16* wproj_t = (u16*)(ws + 14680064);   // 2 MB
    u16* q_bf    = (u16*)(ws + 16777216);   // 8 MB  [bh][t][d] (pre-scaled)
    u16* k_bf    = (u16*)(ws + 25165824);   // 8 MB  [bh][t][d]
    u16* vt_bf   = (u16*)(ws + 33554432);   // 8 MB  [bh][d][t]
    u16* y_bf    = (u16*)(ws + 41943040);   // 8 MB  [b*t][c]

    const int M = B_ * T_;  // 4096

    // fused prep: cast + both weight transposes (2048 blocks)
    prep_kernel<<<2048, 256, 0, stream>>>(x, w_qkv, w_proj, x_bf, wqkv_t, wproj_t);

    // fused QKV: QK (512 blocks) + Vt (256 blocks), coalesced epilogues, 3 blocks/CU
    qkv_gemm<<<768, 256, 0, stream>>>(x_bf, wqkv_t, q_bf, k_bf, vt_bf);

    // flash attention: 1024 4-wave blocks
    attn_kernel<<<32 * (T_ / 64), 256, 0, stream>>>(q_bf, k_bf, vt_bf, y_bf);

    // proj gemm: [4096,1024] x [1024,1024]^T + bias (512 blocks)
    gemm64_proj<<<dim3(C_ / 64, M / 128), 256, 0, stream>>>(
        y_bf, wproj_t, out, b_proj, M, C_, C_);
}

// Round 11
// 169.812 us; speedup vs baseline: 2.2661x; 1.0842x over previous
//
#include <hip/hip_runtime.h>

typedef __bf16 bf16x8 __attribute__((ext_vector_type(8)));
typedef float f32x4 __attribute__((ext_vector_type(4)));
typedef unsigned short u16;
typedef unsigned int u32;
typedef u32 u32x4 __attribute__((ext_vector_type(4)));
typedef u16 u16x8 __attribute__((ext_vector_type(8)));

#define B_ 2
#define T_ 2048
#define C_ 1024
#define H_ 16
#define D_ 64
// 0.125 * log2(e): folded into Q so attn softmax runs in exp2 domain
#define QSCALE 0.18033688011112042f

__device__ __forceinline__ u16 f2bf(float f) {
    u32 u = __builtin_bit_cast(u32, f);
    u += 0x7fffu + ((u >> 16) & 1u);
    return (u16)(u >> 16);
}

__device__ __forceinline__ f32x4 mfma16(bf16x8 a, bf16x8 b, f32x4 c) {
    return __builtin_amdgcn_mfma_f32_16x16x32_bf16(a, b, c, 0, 0, 0);
}

// async global->LDS, 16B per lane; LDS dest = wave-uniform base + lane*16
__device__ __forceinline__ void gll16(const u16* g, u16* l) {
    __builtin_amdgcn_global_load_lds((const __attribute__((address_space(1))) unsigned int*)g,
                                     (__attribute__((address_space(3))) unsigned int*)l,
                                     16, 0, 0);
}

// ---------------- fused prep (verified r8/r9): cast x + transpose w_qkv + w_proj ----------------
__global__ __launch_bounds__(256) void prep_kernel(const float* __restrict__ x,
                                                   const float* __restrict__ w_qkv,
                                                   const float* __restrict__ w_proj,
                                                   u16* __restrict__ x_bf,
                                                   u16* __restrict__ wqkv_t,
                                                   u16* __restrict__ wproj_t) {
    __shared__ float tile[64][65];
    int bid = blockIdx.x;
    int t = threadIdx.x;
    if (bid < 1024) {
        int base = bid * 4096 + t * 4;
#pragma unroll
        for (int it = 0; it < 4; ++it) {
            int i = base + it * 1024;
            float4 v = *(const float4*)(x + i);
            x_bf[i + 0] = f2bf(v.x);
            x_bf[i + 1] = f2bf(v.y);
            x_bf[i + 2] = f2bf(v.z);
            x_bf[i + 3] = f2bf(v.w);
        }
        return;
    }
    const float* in;
    u16* out;
    int N, tidx;
    if (bid < 1792) { in = w_qkv; out = wqkv_t; N = 3 * C_; tidx = bid - 1024; }
    else            { in = w_proj; out = wproj_t; N = C_;  tidx = bid - 1792; }
    int ntiles = N / 64;
    int n0 = (tidx % ntiles) * 64, k0 = (tidx / ntiles) * 64;
    int c = t & 63, r0 = t >> 6;
    for (int i = 0; i < 16; ++i) {
        int r = r0 * 16 + i;
        tile[r][c] = in[(size_t)(k0 + r) * N + n0 + c];
    }
    __syncthreads();
    for (int i = 0; i < 16; ++i) {
        int rn = r0 * 16 + i;
        out[(size_t)(n0 + rn) * C_ + k0 + c] = f2bf(tile[c][rn]);
    }
}

// ---------------- fused QKV GEMM: QK (blocks 0..511) + Vt (blocks 512..767) ----------------
// NEW this round: (a) attn-style double-buffered LDS staging — prefetch of k-tile kt+1
// issued right after the barrier, a full compute-iteration before its use (removes the
// exposed ~500-900cyc vmcnt drain of the old issue-then-barrier loop); (b) swizzle key
// (row>>1)&3 so b128 fragment reads alias exactly 2 lanes/bank (free) instead of 4-way.
// Epilogues verbatim from r9/r10 (coalesced LDS-transpose, 32B/lane stores).
__global__ __launch_bounds__(256) void qkv_gemm(const u16* __restrict__ x_bf,
                                                const u16* __restrict__ wqkv_t,
                                                u16* __restrict__ Qo, u16* __restrict__ Ko,
                                                u16* __restrict__ Vto) {
    __shared__ __align__(16) u16 smem[16384];  // As[2]=[0:8192], Bs[2]=[8192:16384]
    const int K = 1024;
    int bid = blockIdx.x;
    bool qk = (bid < 512);
    const u16 *A, *Bt;
    int m0, n0;
    if (qk) {
        A = x_bf; Bt = wqkv_t;
        n0 = (bid & 15) * 128; m0 = (bid >> 4) * 128;
    } else {
        int vb = bid - 512;
        A = wqkv_t + 2048 * 1024; Bt = x_bf;
        n0 = (vb & 31) * 128; m0 = (vb >> 5) * 128;
    }
    int t = threadIdx.x;
    int wave = t >> 6, lane = t & 63, lr = lane & 15, quad = lane >> 4;
    int wm = (wave >> 1) * 64, wn = (wave & 1) * 64;

    int srow = lane >> 2;                      // 0..15
    int sgl = (lane & 3) ^ ((srow >> 1) & 3);  // conflict-free swizzle key
    int swz = (quad ^ ((lr >> 1) & 3)) * 8;

    f32x4 acc[4][4];
    for (int i = 0; i < 4; ++i)
        for (int j = 0; j < 4; ++j) acc[i][j] = (f32x4){0.f, 0.f, 0.f, 0.f};

    // stage k-tile kb into buffer b
    auto stage = [&](int b, int kb) {
        u16* As = smem + b * 4096;
        u16* Bs = smem + 8192 + b * 4096;
        for (int i = 0; i < 2; ++i) {
            int c = wave * 2 + i;
            int row = c * 16 + srow;
            gll16(&A[(size_t)(m0 + row) * K + kb + sgl * 8], &As[c * 512]);
            gll16(&Bt[(size_t)(n0 + row) * K + kb + sgl * 8], &Bs[c * 512]);
        }
    };

    stage(0, 0);
    for (int kt = 0; kt < 32; ++kt) {
        int buf = kt & 1;
        __syncthreads();  // staging of buf complete; all waves done reading buf^1
        if (kt < 31) stage(buf ^ 1, (kt + 1) * 32);
        const u16* As = smem + buf * 4096;
        const u16* Bs = smem + 8192 + buf * 4096;
        bf16x8 af[4], bfr[4];
        for (int mt = 0; mt < 4; ++mt)
            af[mt] = *(const bf16x8*)&As[(wm + mt * 16 + lr) * 32 + swz];
        for (int nt = 0; nt < 4; ++nt)
            bfr[nt] = *(const bf16x8*)&Bs[(wn + nt * 16 + lr) * 32 + swz];
        for (int mt = 0; mt < 4; ++mt)
            for (int nt = 0; nt < 4; ++nt) acc[mt][nt] = mfma16(af[mt], bfr[nt], acc[mt][nt]);
    }

    // coalesced transposed epilogue (verbatim r9/r10): 4 passes via per-wave LDS buffer
    __syncthreads();  // all waves done with final compute before smem reuse
    u16* eb = smem + wave * 1152;
    int row = lane >> 2;
    int cb = (lane & 3) * 16;
    if (qk) {
        int colg = n0 + wn;
        int part = colg >> 10;
        int h = (colg & 1023) >> 6;
        float sc = (part == 0) ? QSCALE : 1.0f;
        u16* outb = (part == 0) ? Qo : Ko;
#pragma unroll
        for (int p = 0; p < 4; ++p) {
            asm volatile("" ::: "memory");
#pragma unroll
            for (int nt = 0; nt < 4; ++nt)
#pragma unroll
                for (int r = 0; r < 4; ++r)
                    eb[(quad * 4 + r) * 72 + nt * 16 + lr] = f2bf(acc[p][nt][r] * sc);
            asm volatile("" ::: "memory");
            u16x8 va = *(const u16x8*)(eb + row * 72 + cb);
            u16x8 vb = *(const u16x8*)(eb + row * 72 + cb + 8);
            asm volatile("" ::: "memory");
            int rowg = m0 + wm + p * 16 + row;
            int bb = rowg >> 11, tt = rowg & 2047;
            int bh = bb * H_ + h;
            u32* dst = (u32*)(outb + ((size_t)(bh * T_ + tt)) * D_ + cb);
            *(u32x4*)dst = __builtin_bit_cast(u32x4, va);
            *(u32x4*)(dst + 4) = __builtin_bit_cast(u32x4, vb);
        }
    } else {
#pragma unroll
        for (int p = 0; p < 4; ++p) {
            asm volatile("" ::: "memory");
#pragma unroll
            for (int nt = 0; nt < 4; ++nt)
#pragma unroll
                for (int r = 0; r < 4; ++r)
                    eb[(quad * 4 + r) * 72 + nt * 16 + lr] = f2bf(acc[p][nt][r]);
            asm volatile("" ::: "memory");
            u16x8 va = *(const u16x8*)(eb + row * 72 + cb);
            u16x8 vb = *(const u16x8*)(eb + row * 72 + cb + 8);
            asm volatile("" ::: "memory");
            int rowg = m0 + wm + p * 16 + row;
            int h = rowg >> 6, d = rowg & 63;
            int tg = n0 + wn + cb;
            int bb = tg >> 11, tt = tg & 2047;
            u32* dst = (u32*)(Vto + (((size_t)(bb * H_ + h)) * D_ + d) * T_ + tt);
            *(u32x4*)dst = __builtin_bit_cast(u32x4, va);
            *(u32x4*)(dst + 4) = __builtin_bit_cast(u32x4, vb);
        }
    }
}

// ---------------- proj GEMM 128x64 with dbuf staging + conflict-free swizzle ----------------
__global__ __launch_bounds__(256) void gemm64_proj(const u16* __restrict__ A,
                                                   const u16* __restrict__ Bt,
                                                   float* __restrict__ Cout,
                                                   const float* __restrict__ bias,
                                                   int M, int N, int K) {
    __shared__ __align__(16) u16 smem[12288];  // As[2]=[0:8192], Bs[2]=[8192:12288]
    int m0 = blockIdx.y * 128, n0 = blockIdx.x * 64;
    int t = threadIdx.x;
    int wave = t >> 6, lane = t & 63, lr = lane & 15, quad = lane >> 4;
    int srow = lane >> 2;
    int sgl = (lane & 3) ^ ((srow >> 1) & 3);
    int swz = (quad ^ ((lr >> 1) & 3)) * 8;

    f32x4 acc[2][4];
#pragma unroll
    for (int i = 0; i < 2; ++i)
#pragma unroll
        for (int j = 0; j < 4; ++j) acc[i][j] = (f32x4){0.f, 0.f, 0.f, 0.f};

    auto stage = [&](int b, int kb) {
        u16* As = smem + b * 4096;
        u16* Bs = smem + 8192 + b * 2048;
#pragma unroll
        for (int i = 0; i < 2; ++i) {
            int c = wave * 2 + i;
            int row = c * 16 + srow;
            gll16(&A[(size_t)(m0 + row) * K + kb + sgl * 8], &As[c * 512]);
        }
        {
            int row = wave * 16 + srow;
            gll16(&Bt[(size_t)(n0 + row) * K + kb + sgl * 8], &Bs[wave * 512]);
        }
    };

    int niter = K / 32;
    stage(0, 0);
    for (int kt = 0; kt < niter; ++kt) {
        int buf = kt & 1;
        __syncthreads();
        if (kt < niter - 1) stage(buf ^ 1, (kt + 1) * 32);
        const u16* As = smem + buf * 4096;
        const u16* Bs = smem + 8192 + buf * 2048;
        bf16x8 af[2], bfr[4];
#pragma unroll
        for (int mt = 0; mt < 2; ++mt)
            af[mt] = *(const bf16x8*)&As[(wave * 32 + mt * 16 + lr) * 32 + swz];
#pragma unroll
        for (int nt = 0; nt < 4; ++nt)
            bfr[nt] = *(const bf16x8*)&Bs[(nt * 16 + lr) * 32 + swz];
#pragma unroll
        for (int mt = 0; mt < 2; ++mt)
#pragma unroll
            for (int nt = 0; nt < 4; ++nt) acc[mt][nt] = mfma16(af[mt], bfr[nt], acc[mt][nt]);
    }

#pragma unroll
    for (int mt = 0; mt < 2; ++mt)
#pragma unroll
        for (int nt = 0; nt < 4; ++nt)
#pragma unroll
            for (int r = 0; r < 4; ++r) {
                int rowg = m0 + wave * 32 + mt * 16 + quad * 4 + r;
                int col = n0 + nt * 16 + lr;
                Cout[(size_t)rowg * N + col] = acc[mt][nt][r] + bias[col];
            }
}

// ---------------- flash attention (verified r7, verbatim) ----------------
__global__ __launch_bounds__(256, 4) void attn_kernel(const u16* __restrict__ Q,
                                                      const u16* __restrict__ Kb,
                                                      const u16* __restrict__ Vt,
                                                      u16* __restrict__ Y) {
    __shared__ __align__(16) u16 Kls[2][64 * 64];
    __shared__ __align__(16) u16 Vls[2][64 * 64];
    __shared__ __align__(16) u32 Pls[4][512];
    int qt = 31 - (blockIdx.x >> 5);  // heavy-first
    int bh = blockIdx.x & 31;
    int t = threadIdx.x, wave = t >> 6, lane = t & 63, lr = lane & 15, quad = lane >> 4;

    const u16* kbase = Kb + (size_t)bh * (T_ * D_);
    const u16* vbase = Vt + (size_t)bh * (D_ * T_);
    const u16* Qg = Q + ((size_t)bh * T_ + qt * 64 + wave * 16 + lr) * D_;
    bf16x8 qfl = *(const bf16x8*)(Qg + quad * 8);
    bf16x8 qfh = *(const bf16x8*)(Qg + 32 + quad * 8);

    float lsum = 0.f;
    f32x4 o[4];
#pragma unroll
    for (int dt = 0; dt < 4; ++dt) o[dt] = (f32x4){0.f, 0.f, 0.f, 0.f};

    int srow = lane >> 3;
    int sgl = (lane & 7) ^ srow;
    int swz1 = (quad ^ (lr & 7)) * 8;
    int swz2 = ((quad + 4) ^ (lr & 7)) * 8;
    u32* pw = &Pls[wave][0];
    int pwbase = lr * 32 + (quad & 1) * 2;
    int rg1 = (quad ^ (lr & 7)) << 2;
    int rg2 = ((quad + 4) ^ (lr & 7)) << 2;

    for (int i = 0; i < 2; ++i) {
        int c = wave * 2 + i;
        int row = c * 8 + srow;
        gll16(kbase + (size_t)row * D_ + sgl * 8, &Kls[0][c * 512]);
        gll16(vbase + (size_t)row * T_ + sgl * 8, &Vls[0][c * 512]);
    }

    for (int kt = 0; kt <= qt; ++kt) {
        int buf = kt & 1;
        __syncthreads();
        if (kt < qt) {
            int nk = kt + 1;
            for (int i = 0; i < 2; ++i) {
                int c = wave * 2 + i;
                int row = c * 8 + srow;
                gll16(kbase + (size_t)(nk * 64 + row) * D_ + sgl * 8, &Kls[buf ^ 1][c * 512]);
                gll16(vbase + (size_t)row * T_ + nk * 64 + sgl * 8, &Vls[buf ^ 1][c * 512]);
            }
        }
        bf16x8 kf0[4], kf1[4], vf0[4], vf1[4];
#pragma unroll
        for (int st = 0; st < 4; ++st) {
            const u16* kp = &Kls[buf][(st * 16 + lr) * 64];
            kf0[st] = *(const bf16x8*)(kp + swz1);
            kf1[st] = *(const bf16x8*)(kp + swz2);
            const u16* vp = &Vls[buf][(st * 16 + lr) * 64];
            vf0[st] = *(const bf16x8*)(vp + swz1);
            vf1[st] = *(const bf16x8*)(vp + swz2);
        }
        f32x4 s[4];
#pragma unroll
        for (int st = 0; st < 4; ++st) {
            s[st] = mfma16(kf0[st], qfl, (f32x4){0.f, 0.f, 0.f, 0.f});
            s[st] = mfma16(kf1[st], qfh, s[st]);
        }
        if (kt == qt) {
            int qloc = wave * 16 + lr;
#pragma unroll
            for (int st = 0; st < 4; ++st)
#pragma unroll
                for (int r = 0; r < 4; ++r) {
                    if (st * 16 + quad * 4 + r > qloc) s[st][r] = -__builtin_inff();
                }
        }
        float sum = 0.f;
#pragma unroll
        for (int st = 0; st < 4; ++st)
#pragma unroll
            for (int r = 0; r < 4; ++r) {
                float p = __builtin_amdgcn_exp2f(s[st][r]);
                s[st][r] = p;
                sum += p;
            }
        sum += __shfl_xor(sum, 16);
        sum += __shfl_xor(sum, 32);
        lsum += sum;
        asm volatile("" ::: "memory");
#pragma unroll
        for (int st = 0; st < 4; ++st)
#pragma unroll
            for (int rp = 0; rp < 2; ++rp) {
                u32 lo = f2bf(s[st][2 * rp]);
                u32 hi = f2bf(s[st][2 * rp + 1]);
                pw[pwbase + (((st * 2 + (quad >> 1)) ^ (lr & 7)) << 2) + rp] = lo | (hi << 16);
            }
        asm volatile("" ::: "memory");
        const u32* prow = &pw[lr * 32];
        u32x4 plo = *(const u32x4*)(prow + rg1);
        u32x4 phi = *(const u32x4*)(prow + rg2);
        asm volatile("" ::: "memory");
        bf16x8 pfl = __builtin_bit_cast(bf16x8, plo);
        bf16x8 pfh = __builtin_bit_cast(bf16x8, phi);
#pragma unroll
        for (int dt = 0; dt < 4; ++dt) {
            o[dt] = mfma16(vf0[dt], pfl, o[dt]);
            o[dt] = mfma16(vf1[dt], pfh, o[dt]);
        }
    }

    int b = bh >> 4, h = bh & 15;
    float inv = 1.0f / lsum;
    asm volatile("" ::: "memory");
#pragma unroll
    for (int dt = 0; dt < 4; ++dt)
#pragma unroll
        for (int rp = 0; rp < 2; ++rp) {
            u32 lo = f2bf(o[dt][2 * rp] * inv);
            u32 hi = f2bf(o[dt][2 * rp + 1] * inv);
            pw[pwbase + (((dt * 2 + (quad >> 1)) ^ (lr & 7)) << 2) + rp] = lo | (hi << 16);
        }
    asm volatile("" ::: "memory");
    {
        int query = lane >> 2, wsel = lane & 3;
        const u32* prow = &pw[query * 32];
        u32x4 w0 = *(const u32x4*)(prow + (((wsel * 2) ^ (query & 7)) << 2));
        u32x4 w1 = *(const u32x4*)(prow + (((wsel * 2 + 1) ^ (query & 7)) << 2));
        u32* dst = (u32*)(Y + ((size_t)(b * T_ + qt * 64 + wave * 16 + query)) * C_ + h * 64 + wsel * 16);
        *(u32x4*)dst = w0;
        *(u32x4*)(dst + 4) = w1;
    }
}

extern "C" void kernel_launch(void* const* d_in, const int* in_sizes, int n_in,
                              void* d_out, int out_size, void* d_ws, size_t ws_size,
                              hipStream_t stream) {
    const float* x      = (const float*)d_in[0];
    const float* w_qkv  = (const float*)d_in[1];
    const float* w_proj = (const float*)d_in[2];
    const float* b_proj = (const float*)d_in[3];
    float* out = (float*)d_out;

    char* ws = (char*)d_ws;
    u16* x_bf    = (u16*)(ws + 0);          // 8 MB
    u16* wqkv_t  = (u16*)(ws + 8388608);    // 6 MB [n=3072][k=1024]
    u16* wproj_t = (u16*)(ws + 14680064);   // 2 MB
    u16* q_bf    = (u16*)(ws + 16777216);   // 8 MB  [bh][t][d] (pre-scaled)
    u16* k_bf    = (u16*)(ws + 25165824);   // 8 MB  [bh][t][d]
    u16* vt_bf   = (u16*)(ws + 33554432);   // 8 MB  [bh][d][t]
    u16* y_bf    = (u16*)(ws + 41943040);   // 8 MB  [b*t][c]

    const int M = B_ * T_;  // 4096

    // fused prep: cast + both weight transposes (2048 blocks)
    prep_kernel<<<2048, 256, 0, stream>>>(x, w_qkv, w_proj, x_bf, wqkv_t, wproj_t);

    // fused QKV: QK (512 blocks) + Vt (256 blocks), dbuf staging, 3 blocks/CU
    qkv_gemm<<<768, 256, 0, stream>>>(x_bf, wqkv_t, q_bf, k_bf, vt_bf);

    // flash attention: 1024 4-wave blocks
    attn_kernel<<<32 * (T_ / 64), 256, 0, stream>>>(q_bf, k_bf, vt_bf, y_bf);

    // proj gemm: [4096,1024] x [1024,1024]^T + bias (512 blocks, dbuf staging)
    gemm64_proj<<<dim3(C_ / 64, M / 128), 256, 0, stream>>>(
        y_bf, wproj_t, out, b_proj, M, C_, C_);
}